// Round 10
// baseline (22078.514 us; speedup 1.0000x reference)
//
#include <hip/hip_runtime.h>
#include <cstdint>
#include <cstddef>

#define DEV __device__ __forceinline__

typedef float  f32x2  __attribute__((ext_vector_type(2)));
typedef float  f32x4  __attribute__((ext_vector_type(4)));
typedef float  f32x16 __attribute__((ext_vector_type(16)));
typedef int    i32x2  __attribute__((ext_vector_type(2)));
typedef int    i32x4  __attribute__((ext_vector_type(4)));
typedef _Float16 f16x2 __attribute__((ext_vector_type(2)));
typedef _Float16 f16x8 __attribute__((ext_vector_type(8)));

constexpr float DT   = 0.5f;
constexpr float DT3  = 0.5f / 3.0f;
constexpr float DT8  = 0.0625f;

constexpr float S5  = 32.0f,   IS5 = 1.0f / 32.0f;
constexpr float S6  = 64.0f,   IS6 = 1.0f / 64.0f;
constexpr float S8  = 256.0f,  IS8 = 1.0f / 256.0f;
constexpr float S11 = 2048.0f;

// ---- LDS map (bytes) ----
// ACT chain (48K): s_hi[0,16K) s_lo[16K,32K) -> h hi[0,32K) + ALO fp8[32K,48K) -> f f32[0,32K)
constexpr int ACT  = 0;
constexpr int SLO  = 16384;
constexpr int ALO  = 32768;
constexpr int W3H  = 49152;    // 64K fp16 A-frag table W3 hi [4 rg][16 ks][64 lane]*16B
                               //   (first 32K doubles as encoder lo-plane scratch)
constexpr int W3L  = 114688;   // 32K fp8 A-frag table W3 lo*2048 [4 rg][16 ks][64 lane]*8B
constexpr int B2O  = 147456;   // 1K
constexpr int B3O  = 148480;   // 512
constexpr int U01O = 148992;   // 2K
constexpr int SMEM_BYTES = 151040;

#define MFMA16(a, b, c) __builtin_amdgcn_mfma_f32_32x32x16_f16((a), (b), (c), 0, 0, 0)

DEV int swz(int off, int m, int mask) { return off ^ ((m & mask) << 4); }

DEV float tanh_fast(float x) {
  float e = __builtin_amdgcn_exp2f(x * 2.885390082f);
  return 1.0f - 2.0f * __builtin_amdgcn_rcpf(e + 1.0f);
}

DEV unsigned pkh2(float a, float b) {
  f16x2 p = { (_Float16)a, (_Float16)b };
  return __builtin_bit_cast(unsigned, p);
}
DEV float upkh(unsigned u, int hi) {
  f16x2 p = __builtin_bit_cast(f16x2, u);
  return (float)p[hi];
}

DEV f16x8 read_f16t(const char* buf, int RS, int m, int kelem, int mask) {
  return *(const f16x8*)(buf + swz(m * RS + kelem * 2, m, mask));
}
DEV i32x2 read8b(const char* buf, int m, int kelem) {
  return *(const i32x2*)(buf + swz(m * 256 + kelem, m, 15));
}
DEV f16x8 mulh(f16x8 v, float s) {
  _Float16 h = (_Float16)s;
  f16x8 r;
#pragma unroll
  for (int j = 0; j < 8; ++j) r[j] = v[j] * h;
  return r;
}
DEV f16x8 dec8(i32x2 r, float sc) {
  f32x2 p0 = __builtin_amdgcn_cvt_pk_f32_fp8(r[0], false);
  f32x2 p1 = __builtin_amdgcn_cvt_pk_f32_fp8(r[0], true);
  f32x2 p2 = __builtin_amdgcn_cvt_pk_f32_fp8(r[1], false);
  f32x2 p3 = __builtin_amdgcn_cvt_pk_f32_fp8(r[1], true);
  f16x2 q0 = __builtin_bit_cast(f16x2, __builtin_amdgcn_cvt_pkrtz(p0[0] * sc, p0[1] * sc));
  f16x2 q1 = __builtin_bit_cast(f16x2, __builtin_amdgcn_cvt_pkrtz(p1[0] * sc, p1[1] * sc));
  f16x2 q2 = __builtin_bit_cast(f16x2, __builtin_amdgcn_cvt_pkrtz(p2[0] * sc, p2[1] * sc));
  f16x2 q3 = __builtin_bit_cast(f16x2, __builtin_amdgcn_cvt_pkrtz(p3[0] * sc, p3[1] * sc));
  f16x8 o;
  o[0] = q0[0]; o[1] = q0[1]; o[2] = q1[0]; o[3] = q1[1];
  o[4] = q2[0]; o[5] = q2[1]; o[6] = q3[0]; o[7] = q3[1];
  return o;
}
DEV int pk4fp8(float a, float b, float c, float d) {
  int w = __builtin_amdgcn_cvt_pk_fp8_f32(a, b, 0, false);
  w = __builtin_amdgcn_cvt_pk_fp8_f32(c, d, w, true);
  return w;
}
DEV void cvt_h8(const float* p, f16x8& hi, i32x2& lo8) {
  float l[8];
#pragma unroll
  for (int j = 0; j < 8; ++j) {
    float w = p[j]; _Float16 h = (_Float16)w;
    hi[j] = h; l[j] = (w - (float)h) * S11;
  }
  lo8[0] = pk4fp8(l[0], l[1], l[2], l[3]);
  lo8[1] = pk4fp8(l[4], l[5], l[6], l[7]);
}
DEV void cvt_hl_s(const float* p, f16x8& hi, f16x8& lo, float ls) {
  f32x4 a = *(const f32x4*)p;
  f32x4 b = *(const f32x4*)(p + 4);
#pragma unroll
  for (int j = 0; j < 4; ++j) {
    _Float16 h = (_Float16)a[j]; hi[j] = h; lo[j] = (_Float16)((a[j] - (float)h) * ls);
    _Float16 g = (_Float16)b[j]; hi[4 + j] = g; lo[4 + j] = (_Float16)((b[j] - (float)g) * ls);
  }
}

// tanh(acc[2]) -> hi fp16 RS512 + lo*2048 fp8 RS256, rows nbase..nbase+31
DEV void write_h8s(char* hi, char* lo, f32x16 acc[2], int lane, int nbase) {
  const int mr = lane & 31, hh = lane >> 5;
#pragma unroll
  for (int mt = 0; mt < 2; ++mt) {
    int m = mt * 32 + mr;
#pragma unroll
    for (int g = 0; g < 4; ++g) {
      int n = nbase + 8 * g + 4 * hh;
      float v0 = tanh_fast(acc[mt][4 * g + 0]);
      float v1 = tanh_fast(acc[mt][4 * g + 1]);
      float v2 = tanh_fast(acc[mt][4 * g + 2]);
      float v3 = tanh_fast(acc[mt][4 * g + 3]);
      i32x2 w;
      w[0] = (int)pkh2(v0, v1);
      w[1] = (int)pkh2(v2, v3);
      *(i32x2*)(hi + swz(m * 512 + n * 2, m, 31)) = w;
      float l0 = (v0 - (float)(_Float16)v0) * S11;
      float l1 = (v1 - (float)(_Float16)v1) * S11;
      float l2 = (v2 - (float)(_Float16)v2) * S11;
      float l3 = (v3 - (float)(_Float16)v3) * S11;
      *(int*)(lo + swz(m * 256 + n, m, 15)) = pk4fp8(l0, l1, l2, l3);
    }
  }
}

// encoder: relu(acc[2]) hi fp16 + lo*ls fp16, both RS512
DEV void write_h16s(char* hi, char* lo, f32x16 acc[2], int lane, int nbase, float ls) {
  const int mr = lane & 31, hh = lane >> 5;
#pragma unroll
  for (int mt = 0; mt < 2; ++mt) {
    int m = mt * 32 + mr;
#pragma unroll
    for (int g = 0; g < 4; ++g) {
      int n = nbase + 8 * g + 4 * hh;
      float v0 = fmaxf(acc[mt][4 * g + 0], 0.f);
      float v1 = fmaxf(acc[mt][4 * g + 1], 0.f);
      float v2 = fmaxf(acc[mt][4 * g + 2], 0.f);
      float v3 = fmaxf(acc[mt][4 * g + 3], 0.f);
      i32x2 w;
      w[0] = (int)pkh2(v0, v1); w[1] = (int)pkh2(v2, v3);
      *(i32x2*)(hi + swz(m * 512 + n * 2, m, 31)) = w;
      w[0] = (int)pkh2((v0 - (float)(_Float16)v0) * ls, (v1 - (float)(_Float16)v1) * ls);
      w[1] = (int)pkh2((v2 - (float)(_Float16)v2) * ls, (v3 - (float)(_Float16)v3) * ls);
      *(i32x2*)(lo + swz(m * 512 + n * 2, m, 31)) = w;
    }
  }
}

DEV void write_hcs(char* hi, f32x16 acc[2], int lane, int nbase) {
  const int mr = lane & 31, hh = lane >> 5;
#pragma unroll
  for (int mt = 0; mt < 2; ++mt) {
    int m = mt * 32 + mr;
#pragma unroll
    for (int g = 0; g < 4; ++g) {
      int n = nbase + 8 * g + 4 * hh;
      i32x2 w;
      w[0] = (int)pkh2(fmaxf(acc[mt][4 * g + 0], 0.f), fmaxf(acc[mt][4 * g + 1], 0.f));
      w[1] = (int)pkh2(fmaxf(acc[mt][4 * g + 2], 0.f), fmaxf(acc[mt][4 * g + 3], 0.f));
      *(i32x2*)(hi + swz(m * 512 + n * 2, m, 31)) = w;
    }
  }
}

// single acc: D rows nbase.., batch cols mbase+mr -> f32 RS512
DEV void write_f32s(char* dst, const f32x16& a, int lane, int nbase, int mbase) {
  const int mr = lane & 31, hh = lane >> 5;
  int m = mbase + mr;
#pragma unroll
  for (int g = 0; g < 4; ++g) {
    int n = nbase + 8 * g + 4 * hh;
    f32x4 v = { a[4 * g + 0], a[4 * g + 1], a[4 * g + 2], a[4 * g + 3] };
    *(f32x4*)(dst + swz(m * 512 + n * 4, m, 31)) = v;
  }
}

// owners: m = tid>>3 (row), cs = tid&7 (16-elem chunk)
DEV void read_kv16(const char* sm, int m, int cs, float* kv) {
#pragma unroll
  for (int g = 0; g < 4; ++g) {
    f32x4 v = *(const f32x4*)(sm + ACT + swz(m * 512 + cs * 64 + g * 16, m, 31));
    kv[4 * g] = v[0]; kv[4 * g + 1] = v[1]; kv[4 * g + 2] = v[2]; kv[4 * g + 3] = v[3];
  }
}
DEV void write_stage16(char* sm, int m, int cs, const float* sv) {
#pragma unroll
  for (int gg = 0; gg < 2; ++gg) {
    i32x4 wh, wl;
#pragma unroll
    for (int j = 0; j < 4; ++j) {
      float v0 = sv[8 * gg + 2 * j], v1 = sv[8 * gg + 2 * j + 1];
      _Float16 h0 = (_Float16)v0, h1 = (_Float16)v1;
      f16x2 ph = { h0, h1 };
      f16x2 pl = { (_Float16)((v0 - (float)h0) * S5), (_Float16)((v1 - (float)h1) * S5) };
      wh[j] = __builtin_bit_cast(int, ph);
      wl[j] = __builtin_bit_cast(int, pl);
    }
    int off = swz(m * 256 + cs * 32 + gg * 16, m, 15);
    *(i32x4*)(sm + ACT + off) = wh;
    *(i32x4*)(sm + SLO + off) = wl;
  }
}

// ---- one MLP eval: s -> f.  W1/W2 in registers; W3 from LDS tables. ZERO global.
//      Layers 1-2 compute batch-halves SEQUENTIALLY to cut peak register pressure. ----
DEV void f_eval(char* sm, float t,
                const f16x8* W1h, const i32x2* W1l8,
                const f16x8* W2h, const i32x2* W2l8,
                f16x8 Au, int lane, int wave) {
  const int mr = lane & 31, kh = (lane >> 5) * 8, hh = lane >> 5;
  const int nb1 = wave * 32;
  const int rg = wave >> 1, mb3 = (wave & 1) * 32 + mr;

  __syncthreads();  // A: stage visible

  // U-slice B-frags (built once)
  f16x8 ub, ul;
  {
    _Float16 th = (_Float16)t;
    _Float16 tl = (_Float16)(t - (float)th);
#pragma unroll
    for (int j = 0; j < 8; ++j) { ub[j] = (_Float16)0.f; ul[j] = (_Float16)0.f; }
    if (kh == 0) {
      ub[0] = (_Float16)1.0f; ub[1] = th;
      ub[2] = (_Float16)IS8;  ub[3] = (_Float16)((float)th * IS8);
      ul[1] = tl;             ul[3] = (_Float16)((float)tl * IS8);
    }
  }

  f32x16 a1[2];
#pragma unroll
  for (int mt = 0; mt < 2; ++mt) {
    int mb = mt * 32 + mr;
    f32x16 acc;
#pragma unroll
    for (int r = 0; r < 16; ++r) acc[r] = 0.f;
#pragma unroll
    for (int ks = 0; ks < 8; ++ks) {
      int ke = ks * 16 + kh;
      f16x8 bh = read_f16t(sm + ACT, 256, mb, ke, 15);
      f16x8 bl = read_f16t(sm + SLO, 256, mb, ke, 15);
      f16x8 bhm = mulh(bh, IS6);
      f16x8 h = W1h[ks];
      f16x8 w1s = mulh(h, IS5);
      f16x8 l = dec8(W1l8[ks], IS5);
      acc = MFMA16(h, bh, acc);      // s_hi @ W1_hi
      acc = MFMA16(w1s, bl, acc);    // (s_lo*32) @ (W1_hi/32)
      acc = MFMA16(l, bhm, acc);     // (s_hi/64) @ (W1_lo*64)
    }
    acc = MFMA16(Au, ub, acc);
    acc = MFMA16(Au, ul, acc);
    a1[mt] = acc;
  }
  __syncthreads();  // G1: s reads done
  write_h8s(sm + ACT, sm + ALO, a1, lane, nb1);
  __syncthreads();  // C: h1 ready

  // ---- layer 2: W2 hi + lo fp8 from registers, sequential batch halves ----
  const float* B2p = (const float*)(sm + B2O);
  f32x16 a2[2];
#pragma unroll
  for (int mt = 0; mt < 2; ++mt) {
    int mb = mt * 32 + mr;
    f32x16 acc;
#pragma unroll
    for (int g = 0; g < 4; ++g) {
      int n = nb1 + 8 * g + 4 * hh;
      f32x4 bv = *(const f32x4*)(B2p + n);
#pragma unroll
      for (int r = 0; r < 4; ++r) acc[4 * g + r] = bv[r];
    }
#pragma unroll
    for (int ks = 0; ks < 16; ++ks) {
      int ke = ks * 16 + kh;
      f16x8 bh = read_f16t(sm + ACT, 512, mb, ke, 31);
      f16x8 bl = dec8(read8b(sm + ALO, mb, ke), IS6);
      f16x8 W2hv = W2h[ks];
      f16x8 w2s = mulh(W2hv, IS5);
      f16x8 bhm = mulh(bh, IS6);
      f16x8 wa = dec8(W2l8[ks], IS5);
      acc = MFMA16(W2hv, bh, acc);
      acc = MFMA16(w2s, bl, acc);
      acc = MFMA16(wa, bhm, acc);
    }
    a2[mt] = acc;
  }
  __syncthreads();  // G2: h1 reads done
  write_h8s(sm + ACT, sm + ALO, a2, lane, nb1);
  __syncthreads();  // E: h2 ready

  // ---- layer 3: W3 hi fp16 + lo fp8 from LDS tables (pair-shared rg slice) ----
  const float* B3p = (const float*)(sm + B3O);
  f32x16 a3;
#pragma unroll
  for (int g = 0; g < 4; ++g) {
    int n = rg * 32 + 8 * g + 4 * hh;
    f32x4 bv = *(const f32x4*)(B3p + n);
#pragma unroll
    for (int r = 0; r < 4; ++r) a3[4 * g + r] = bv[r];
  }
#pragma unroll
  for (int ks = 0; ks < 16; ++ks) {
    int ke = ks * 16 + kh;
    f16x8 bh = read_f16t(sm + ACT, 512, mb3, ke, 31);
    f16x8 bl = dec8(read8b(sm + ALO, mb3, ke), IS6);
    f16x8 W3hv = *(const f16x8*)(sm + W3H + ((size_t)(rg * 16 + ks) * 64 + lane) * 16);
    i32x2 t0 = *(const i32x2*)(sm + W3L + ((size_t)(rg * 16 + ks) * 64 + lane) * 8);
    f16x8 w3s = mulh(W3hv, IS5);
    f16x8 bhm = mulh(bh, IS6);
    f16x8 wa = dec8(t0, IS5);
    a3 = MFMA16(W3hv, bh, a3);
    a3 = MFMA16(w3s, bl, a3);
    a3 = MFMA16(wa, bhm, a3);
  }
  __syncthreads();  // G3: h2 reads done
  write_f32s(sm + ACT, a3, lane, rg * 32, (wave & 1) * 32);
  __syncthreads();  // F: f ready
}

__global__ __attribute__((amdgpu_flat_work_group_size(512, 512), amdgpu_waves_per_eu(2, 2)))
void node_kernel(
    const float* __restrict__ traj,
    const float* __restrict__ We1, const float* __restrict__ be1,
    const float* __restrict__ We2, const float* __restrict__ be2,
    const float* __restrict__ wte, const float* __restrict__ bte,
    const float* __restrict__ W1,  const float* __restrict__ b1,
    const float* __restrict__ W2,  const float* __restrict__ b2,
    const float* __restrict__ W3,  const float* __restrict__ b3,
    const float* __restrict__ Wc1, const float* __restrict__ bc1,
    const float* __restrict__ Wc2, const float* __restrict__ bc2,
    float* __restrict__ out) {
  __shared__ __align__(16) char sm[SMEM_BYTES];
  const int tid  = threadIdx.x;
  const int lane = tid & 63, wave = tid >> 6;
  const int mr = lane & 31, kh = (lane >> 5) * 8, hh = lane >> 5;
  const int nb1 = wave * 32;
  const int rg = wave >> 1, mb3 = (wave & 1) * 32 + mr;
  const int brow = blockIdx.x * 64;

  // ---- init: U0/U1 fold, bias tables ----
  if (tid < 256) {
    int n = tid;
    float u0 = b1[n], u1 = 0.f;
    const float* wr = W1 + n * 128;
    for (int k = 0; k < 128; ++k) { float w = wr[k]; u1 += wte[k] * w; u0 += bte[k] * w; }
    float* U = (float*)(sm + U01O);
    U[2 * n] = u0; U[2 * n + 1] = u1;
    ((float*)(sm + B2O))[n] = b2[n];
    if (n < 128) ((float*)(sm + B3O))[n] = b3[n];
  }

  // ---- resident registers: W1 hi+lo8, W2 hi+lo8 (wave's 32 rows) ----
  f16x8 W1h[8], W2h[16];
  i32x2 W1l8[8], W2l8[16];
#pragma unroll
  for (int ks = 0; ks < 8; ++ks)
    cvt_h8(W1 + (size_t)(nb1 + mr) * 128 + ks * 16 + kh, W1h[ks], W1l8[ks]);
#pragma unroll
  for (int ks = 0; ks < 16; ++ks)
    cvt_h8(W2 + (size_t)(nb1 + mr) * 256 + ks * 16 + kh, W2h[ks], W2l8[ks]);
  __syncthreads();  // U01 ready

  f16x8 Au;
  {
#pragma unroll
    for (int j = 0; j < 8; ++j) Au[j] = (_Float16)0.f;
    if (kh == 0) {
      const float* U = (const float*)(sm + U01O);
      int n = nb1 + mr;
      float u0 = U[2 * n], u1 = U[2 * n + 1];
      _Float16 u0h = (_Float16)u0, u1h = (_Float16)u1;
      Au[0] = u0h; Au[1] = u1h;
      Au[2] = (_Float16)((u0 - (float)u0h) * S8);
      Au[3] = (_Float16)((u1 - (float)u1h) * S8);
    }
  }

  const int m_own = tid >> 3, cs = tid & 7;

  // ---- encoder: x hi@ACT RS512, x lo*64 @W3H scratch RS512 ----
  f32x16 ae[2];
#pragma unroll
  for (int mt = 0; mt < 2; ++mt)
#pragma unroll
    for (int r = 0; r < 16; ++r) ae[mt][r] = 0.f;

  for (int c = 0; c < 3; ++c) {
#pragma unroll
    for (int q = 0; q < 4; ++q) {
      const float* xp = traj + (size_t)(brow + m_own) * 7168 + c * 256 + cs * 32 + q * 8;
      f32x4 a = *(const f32x4*)xp;
      f32x4 b = *(const f32x4*)(xp + 4);
      i32x4 wh, wl;
#pragma unroll
      for (int j = 0; j < 2; ++j) {
        float v0 = a[2 * j], v1 = a[2 * j + 1];
        _Float16 h0 = (_Float16)v0, h1 = (_Float16)v1;
        f16x2 ph = { h0, h1 };
        f16x2 pl = { (_Float16)((v0 - (float)h0) * S6), (_Float16)((v1 - (float)h1) * S6) };
        wh[j] = __builtin_bit_cast(int, ph); wl[j] = __builtin_bit_cast(int, pl);
        float w0 = b[2 * j], w1 = b[2 * j + 1];
        _Float16 g0 = (_Float16)w0, g1 = (_Float16)w1;
        f16x2 qh = { g0, g1 };
        f16x2 ql = { (_Float16)((w0 - (float)g0) * S6), (_Float16)((w1 - (float)g1) * S6) };
        wh[2 + j] = __builtin_bit_cast(int, qh); wl[2 + j] = __builtin_bit_cast(int, ql);
      }
      int off = swz(m_own * 512 + cs * 64 + q * 16, m_own, 31);
      *(i32x4*)(sm + ACT + off) = wh;
      *(i32x4*)(sm + W3H + off) = wl;
    }
    __syncthreads();
#pragma unroll
    for (int ks = 0; ks < 16; ++ks) {
      int ke = ks * 16 + kh;
      f16x8 bh0 = read_f16t(sm + ACT, 512, mr, ke, 31);
      f16x8 bh1 = read_f16t(sm + ACT, 512, 32 + mr, ke, 31);
      f16x8 bl0 = read_f16t(sm + W3H, 512, mr, ke, 31);
      f16x8 bl1 = read_f16t(sm + W3H, 512, 32 + mr, ke, 31);
      f16x8 bh0m = mulh(bh0, IS6), bh1m = mulh(bh1, IS6);
      f16x8 wh, wl;
      cvt_hl_s(We1 + (size_t)(nb1 + mr) * 768 + c * 256 + ks * 16 + kh, wh, wl, S6);
      f16x8 whs = mulh(wh, IS6);
      ae[0] = MFMA16(wh, bh0, ae[0]);
      ae[1] = MFMA16(wh, bh1, ae[1]);
      ae[0] = MFMA16(whs, bl0, ae[0]);
      ae[1] = MFMA16(whs, bl1, ae[1]);
      ae[0] = MFMA16(wl, bh0m, ae[0]);
      ae[1] = MFMA16(wl, bh1m, ae[1]);
    }
    __syncthreads();
  }
#pragma unroll
  for (int r = 0; r < 16; ++r) {
    int n = nb1 + (r & 3) + 8 * (r >> 2) + 4 * hh;
    float bv = be1[n];
    ae[0][r] += bv; ae[1][r] += bv;
  }
  write_h16s(sm + ACT, sm + W3H, ae, lane, nb1, S6);   // h_enc hi@ACT, lo*64@W3H scratch
  __syncthreads();

  {
    f32x16 az;
#pragma unroll
    for (int r = 0; r < 16; ++r) az[r] = 0.f;
#pragma unroll
    for (int ks = 0; ks < 16; ++ks) {
      int ke = ks * 16 + kh;
      f16x8 bh = read_f16t(sm + ACT, 512, mb3, ke, 31);
      f16x8 bl = read_f16t(sm + W3H, 512, mb3, ke, 31);
      f16x8 bhm = mulh(bh, IS6);
      f16x8 wh, wl;
      cvt_hl_s(We2 + (size_t)(rg * 32 + mr) * 256 + ks * 16 + kh, wh, wl, S6);
      f16x8 whs = mulh(wh, IS6);
      az = MFMA16(wh, bh, az);
      az = MFMA16(whs, bl, az);
      az = MFMA16(wl, bhm, az);
    }
#pragma unroll
    for (int r = 0; r < 16; ++r) {
      int n = rg * 32 + (r & 3) + 8 * (r >> 2) + 4 * hh;
      az[r] += be2[n];
    }
    __syncthreads();                    // h_enc reads done
    write_f32s(sm + ACT, az, lane, rg * 32, (wave & 1) * 32);  // z0
    __syncthreads();
  }

  // ---- owners pick up z0; write frame 0 ----
  float z[16];
  unsigned kdp[8];
  read_kv16(sm, m_own, cs, z);
  float* outz = out + 16384;
  {
    float* p = outz + (size_t)(brow + m_own) * 128 + cs * 16;
#pragma unroll
    for (int g = 0; g < 4; ++g) {
      f32x4 v = { z[4 * g], z[4 * g + 1], z[4 * g + 2], z[4 * g + 3] };
      *(f32x4*)(p + 4 * g) = v;
    }
  }
  __syncthreads();  // z0 reads + W3H-scratch use done

  // ---- fill W3 LDS tables (one-time; waves 0..3 own rg slices) ----
  if (wave < 4) {
    int trg = wave;
#pragma unroll
    for (int ks = 0; ks < 16; ++ks) {
      f16x8 hi; i32x2 lo8;
      cvt_h8(W3 + (size_t)(trg * 32 + mr) * 256 + ks * 16 + kh, hi, lo8);
      *(f16x8*)(sm + W3H + ((size_t)(trg * 16 + ks) * 64 + lane) * 16) = hi;
      *(i32x2*)(sm + W3L + ((size_t)(trg * 16 + ks) * 64 + lane) * 8) = lo8;
    }
  }

  // ---- RK4 (3/8 rule), 54 steps; Acc in regs; ZERO global traffic ----
  float A[16];
  for (int st = 0; st < 54; ++st) {
    float t0 = st * 0.5f;
    __syncthreads();  // H: f/z0 reads done (st=0: W3 tables visible)
    write_stage16(sm, m_own, cs, z);                          // s1 = z
    f_eval(sm, t0, W1h, W1l8, W2h, W2l8, Au, lane, wave);     // k1
    {
      float kv[16], sv[16];
      read_kv16(sm, m_own, cs, kv);
      __syncthreads();
#pragma unroll
      for (int e = 0; e < 16; ++e) {
        A[e] = z[e] + DT8 * kv[e];
        sv[e] = z[e] + DT3 * kv[e];
      }
#pragma unroll
      for (int i = 0; i < 8; ++i) kdp[i] = pkh2(kv[2 * i], kv[2 * i + 1]);
      write_stage16(sm, m_own, cs, sv);
    }
    f_eval(sm, t0 + DT3, W1h, W1l8, W2h, W2l8, Au, lane, wave);  // k2
    {
      float kv[16], sv[16];
      read_kv16(sm, m_own, cs, kv);
      __syncthreads();
#pragma unroll
      for (int i = 0; i < 8; ++i) {
        float k1a = upkh(kdp[i], 0), k1b = upkh(kdp[i], 1);
        A[2 * i]     += 3.0f * DT8 * kv[2 * i];
        A[2 * i + 1] += 3.0f * DT8 * kv[2 * i + 1];
        sv[2 * i]     = z[2 * i]     + DT * kv[2 * i]     - DT3 * k1a;
        sv[2 * i + 1] = z[2 * i + 1] + DT * kv[2 * i + 1] - DT3 * k1b;
        kdp[i] = pkh2(k1a - kv[2 * i], k1b - kv[2 * i + 1]);   // d12
      }
      write_stage16(sm, m_own, cs, sv);
    }
    f_eval(sm, t0 + 2.0f * DT3, W1h, W1l8, W2h, W2l8, Au, lane, wave);  // k3
    {
      float kv[16], sv[16];
      read_kv16(sm, m_own, cs, kv);
      __syncthreads();
#pragma unroll
      for (int i = 0; i < 8; ++i) {
        float da = upkh(kdp[i], 0), db = upkh(kdp[i], 1);
        A[2 * i]     += 3.0f * DT8 * kv[2 * i];
        A[2 * i + 1] += 3.0f * DT8 * kv[2 * i + 1];
        sv[2 * i]     = z[2 * i]     + DT * (da + kv[2 * i]);
        sv[2 * i + 1] = z[2 * i + 1] + DT * (db + kv[2 * i + 1]);
      }
      write_stage16(sm, m_own, cs, sv);
    }
    f_eval(sm, t0 + DT, W1h, W1l8, W2h, W2l8, Au, lane, wave);   // k4
    {
      float kv[16];
      read_kv16(sm, m_own, cs, kv);
#pragma unroll
      for (int e = 0; e < 16; ++e) z[e] = A[e] + DT8 * kv[e];
    }
    if (st & 1) {
      int frame = (st >> 1) + 1;
      float* p = outz + (size_t)frame * 2097152 + (size_t)(brow + m_own) * 128 + cs * 16;
#pragma unroll
      for (int g = 0; g < 4; ++g) {
        f32x4 v = { z[4 * g], z[4 * g + 1], z[4 * g + 2], z[4 * g + 3] };
        *(f32x4*)(p + 4 * g) = v;
      }
    }
  }

  // ---- classifier ----
  __syncthreads();  // f reads done
  write_stage16(sm, m_own, cs, z);
  __syncthreads();
  f32x16 ac[2];
#pragma unroll
  for (int r = 0; r < 16; ++r) {
    int n = nb1 + (r & 3) + 8 * (r >> 2) + 4 * hh;
    float bv = bc1[n];
    ac[0][r] = bv; ac[1][r] = bv;
  }
#pragma unroll
  for (int ks = 0; ks < 8; ++ks) {
    int ke = ks * 16 + kh;
    f16x8 bh0 = read_f16t(sm + ACT, 256, mr, ke, 15);
    f16x8 bh1 = read_f16t(sm + ACT, 256, 32 + mr, ke, 15);
    f16x8 bl0 = read_f16t(sm + SLO, 256, mr, ke, 15);
    f16x8 bl1 = read_f16t(sm + SLO, 256, 32 + mr, ke, 15);
    f16x8 wh, wl;
    cvt_hl_s(Wc1 + (size_t)(nb1 + mr) * 128 + ks * 16 + kh, wh, wl, 1.0f);
    f16x8 whs = mulh(wh, IS5);
    ac[0] = MFMA16(wh, bh0, ac[0]);
    ac[1] = MFMA16(wh, bh1, ac[1]);
    ac[0] = MFMA16(whs, bl0, ac[0]);
    ac[1] = MFMA16(whs, bl1, ac[1]);
    ac[0] = MFMA16(wl, bh0, ac[0]);
    ac[1] = MFMA16(wl, bh1, ac[1]);
  }
  __syncthreads();  // s reads done
  write_hcs(sm + ACT, ac, lane, nb1);
  __syncthreads();
  if (tid < 64) {
    float acc = bc2[0];
#pragma unroll 8
    for (int c0 = 0; c0 < 256; c0 += 8) {
      f16x8 hv = read_f16t(sm + ACT, 512, tid, c0, 31);
#pragma unroll
      for (int j = 0; j < 8; ++j) acc += (float)hv[j] * Wc2[c0 + j];
    }
    out[brow + tid] = __builtin_amdgcn_rcpf(1.0f + __builtin_amdgcn_exp2f(-acc * 1.442695041f));
  }
}

extern "C" void kernel_launch(void* const* d_in, const int* in_sizes, int n_in,
                              void* d_out, int out_size, void* d_ws, size_t ws_size,
                              hipStream_t stream) {
  (void)in_sizes; (void)n_in; (void)out_size; (void)d_ws; (void)ws_size;
  const float* traj = (const float*)d_in[0];
  const float* We1  = (const float*)d_in[1];
  const float* be1  = (const float*)d_in[2];
  const float* We2  = (const float*)d_in[3];
  const float* be2  = (const float*)d_in[4];
  const float* wte  = (const float*)d_in[5];
  const float* bte  = (const float*)d_in[6];
  const float* W1   = (const float*)d_in[7];
  const float* b1   = (const float*)d_in[8];
  const float* W2   = (const float*)d_in[9];
  const float* b2   = (const float*)d_in[10];
  const float* W3   = (const float*)d_in[11];
  const float* b3   = (const float*)d_in[12];
  const float* Wc1  = (const float*)d_in[13];
  const float* bc1  = (const float*)d_in[14];
  const float* Wc2  = (const float*)d_in[15];
  const float* bc2  = (const float*)d_in[16];
  hipLaunchKernelGGL(node_kernel, dim3(256), dim3(512), 0, stream,
                     traj, We1, be1, We2, be2, wte, bte, W1, b1, W2, b2, W3, b3,
                     Wc1, bc1, Wc2, bc2, (float*)d_out);
}

// Round 12
// 8758.076 us; speedup vs baseline: 2.5209x; 2.5209x over previous
//
#include <hip/hip_runtime.h>
#include <cstdint>
#include <cstddef>

#define DEV __device__ __forceinline__

typedef float  f32x2  __attribute__((ext_vector_type(2)));
typedef float  f32x4  __attribute__((ext_vector_type(4)));
typedef float  f32x16 __attribute__((ext_vector_type(16)));
typedef int    i32x2  __attribute__((ext_vector_type(2)));
typedef int    i32x4  __attribute__((ext_vector_type(4)));
typedef _Float16 f16x2 __attribute__((ext_vector_type(2)));
typedef _Float16 f16x8 __attribute__((ext_vector_type(8)));

constexpr float DT   = 0.5f;
constexpr float DT3  = 0.5f / 3.0f;
constexpr float DT8  = 0.0625f;

constexpr float S5  = 32.0f,   IS5 = 1.0f / 32.0f;
constexpr float S6  = 64.0f,   IS6 = 1.0f / 64.0f;
constexpr float S8  = 256.0f,  IS8 = 1.0f / 256.0f;
constexpr float S11 = 2048.0f;

// ---- LDS map (bytes) ----
// ACT chain (48K): s_hi[0,16K) s_lo[16K,32K) -> h hi[0,32K) + ALO fp8[32K,48K) -> f f32[0,32K)
constexpr int ACT  = 0;
constexpr int SLO  = 16384;
constexpr int ALO  = 32768;
constexpr int W2L  = 49152;    // 64K: fp8 table W2_lo*2048  ((wave*2+nt)*16+ks)*64+lane)*8
                               //   (first 32K doubles as encoder lo-plane scratch)
constexpr int W3L  = 114688;   // 32K: fp8 table W3_lo*2048  ((wave*16+ks)*64+lane)*8
constexpr int B2O  = 147456;   // 1K
constexpr int B3O  = 148480;   // 512
constexpr int U01O = 148992;   // 2K
constexpr int SMEM_BYTES = 151040;

#define MFMA16(a, b, c) __builtin_amdgcn_mfma_f32_32x32x16_f16((a), (b), (c), 0, 0, 0)

DEV int swz(int off, int m, int mask) { return off ^ ((m & mask) << 4); }

DEV float tanh_fast(float x) {
  float e = __builtin_amdgcn_exp2f(x * 2.885390082f);
  return 1.0f - 2.0f * __builtin_amdgcn_rcpf(e + 1.0f);
}

DEV unsigned pkh2(float a, float b) {
  f16x2 p = { (_Float16)a, (_Float16)b };
  return __builtin_bit_cast(unsigned, p);
}
DEV float upkh(unsigned u, int hi) {
  f16x2 p = __builtin_bit_cast(f16x2, u);
  return (float)p[hi];
}

DEV f16x8 read_f16t(const char* buf, int RS, int m, int kelem, int mask) {
  return *(const f16x8*)(buf + swz(m * RS + kelem * 2, m, mask));
}
DEV i32x2 read8b(const char* buf, int m, int kelem) {
  return *(const i32x2*)(buf + swz(m * 256 + kelem, m, 15));
}
DEV f16x8 mulh(f16x8 v, float s) {
  _Float16 h = (_Float16)s;
  f16x8 r;
#pragma unroll
  for (int j = 0; j < 8; ++j) r[j] = v[j] * h;
  return r;
}
DEV f16x8 dec8(i32x2 r, float sc) {
  f32x2 p0 = __builtin_amdgcn_cvt_pk_f32_fp8(r[0], false);
  f32x2 p1 = __builtin_amdgcn_cvt_pk_f32_fp8(r[0], true);
  f32x2 p2 = __builtin_amdgcn_cvt_pk_f32_fp8(r[1], false);
  f32x2 p3 = __builtin_amdgcn_cvt_pk_f32_fp8(r[1], true);
  f16x2 q0 = __builtin_bit_cast(f16x2, __builtin_amdgcn_cvt_pkrtz(p0[0] * sc, p0[1] * sc));
  f16x2 q1 = __builtin_bit_cast(f16x2, __builtin_amdgcn_cvt_pkrtz(p1[0] * sc, p1[1] * sc));
  f16x2 q2 = __builtin_bit_cast(f16x2, __builtin_amdgcn_cvt_pkrtz(p2[0] * sc, p2[1] * sc));
  f16x2 q3 = __builtin_bit_cast(f16x2, __builtin_amdgcn_cvt_pkrtz(p3[0] * sc, p3[1] * sc));
  f16x8 o;
  o[0] = q0[0]; o[1] = q0[1]; o[2] = q1[0]; o[3] = q1[1];
  o[4] = q2[0]; o[5] = q2[1]; o[6] = q3[0]; o[7] = q3[1];
  return o;
}
DEV int pk4fp8(float a, float b, float c, float d) {
  int w = __builtin_amdgcn_cvt_pk_fp8_f32(a, b, 0, false);
  w = __builtin_amdgcn_cvt_pk_fp8_f32(c, d, w, true);
  return w;
}
DEV void cvt_h8(const float* p, f16x8& hi, i32x2& lo8) {
  float l[8];
#pragma unroll
  for (int j = 0; j < 8; ++j) {
    float w = p[j]; _Float16 h = (_Float16)w;
    hi[j] = h; l[j] = (w - (float)h) * S11;
  }
  lo8[0] = pk4fp8(l[0], l[1], l[2], l[3]);
  lo8[1] = pk4fp8(l[4], l[5], l[6], l[7]);
}
DEV void cvt_hl_s(const float* p, f16x8& hi, f16x8& lo, float ls) {
  f32x4 a = *(const f32x4*)p;
  f32x4 b = *(const f32x4*)(p + 4);
#pragma unroll
  for (int j = 0; j < 4; ++j) {
    _Float16 h = (_Float16)a[j]; hi[j] = h; lo[j] = (_Float16)((a[j] - (float)h) * ls);
    _Float16 g = (_Float16)b[j]; hi[4 + j] = g; lo[4 + j] = (_Float16)((b[j] - (float)g) * ls);
  }
}
DEV f16x8 cvt8v(f32x4 a, f32x4 b) {
  f16x8 h;
#pragma unroll
  for (int j = 0; j < 4; ++j) { h[j] = (_Float16)a[j]; h[4 + j] = (_Float16)b[j]; }
  return h;
}

// tanh(acc) -> hi fp16 RS512 + lo*2048 fp8 RS256
DEV void write_h8(char* hi, char* lo, f32x16 acc[2][2], int lane, int nbase) {
  const int mr = lane & 31, hh = lane >> 5;
#pragma unroll
  for (int nt = 0; nt < 2; ++nt)
#pragma unroll
    for (int mt = 0; mt < 2; ++mt) {
      int m = mt * 32 + mr;
#pragma unroll
      for (int g = 0; g < 4; ++g) {
        int n = nbase + nt * 32 + 8 * g + 4 * hh;
        float v0 = tanh_fast(acc[nt][mt][4 * g + 0]);
        float v1 = tanh_fast(acc[nt][mt][4 * g + 1]);
        float v2 = tanh_fast(acc[nt][mt][4 * g + 2]);
        float v3 = tanh_fast(acc[nt][mt][4 * g + 3]);
        i32x2 w;
        w[0] = (int)pkh2(v0, v1);
        w[1] = (int)pkh2(v2, v3);
        *(i32x2*)(hi + swz(m * 512 + n * 2, m, 31)) = w;
        float l0 = (v0 - (float)(_Float16)v0) * S11;
        float l1 = (v1 - (float)(_Float16)v1) * S11;
        float l2 = (v2 - (float)(_Float16)v2) * S11;
        float l3 = (v3 - (float)(_Float16)v3) * S11;
        *(int*)(lo + swz(m * 256 + n, m, 15)) = pk4fp8(l0, l1, l2, l3);
      }
    }
}

// encoder: relu(acc) hi fp16 + lo*ls fp16, both RS512
DEV void write_h16(char* hi, char* lo, f32x16 acc[2][2], int lane, int nbase, float ls) {
  const int mr = lane & 31, hh = lane >> 5;
#pragma unroll
  for (int nt = 0; nt < 2; ++nt)
#pragma unroll
    for (int mt = 0; mt < 2; ++mt) {
      int m = mt * 32 + mr;
#pragma unroll
      for (int g = 0; g < 4; ++g) {
        int n = nbase + nt * 32 + 8 * g + 4 * hh;
        float v0 = fmaxf(acc[nt][mt][4 * g + 0], 0.f);
        float v1 = fmaxf(acc[nt][mt][4 * g + 1], 0.f);
        float v2 = fmaxf(acc[nt][mt][4 * g + 2], 0.f);
        float v3 = fmaxf(acc[nt][mt][4 * g + 3], 0.f);
        i32x2 w;
        w[0] = (int)pkh2(v0, v1); w[1] = (int)pkh2(v2, v3);
        *(i32x2*)(hi + swz(m * 512 + n * 2, m, 31)) = w;
        w[0] = (int)pkh2((v0 - (float)(_Float16)v0) * ls, (v1 - (float)(_Float16)v1) * ls);
        w[1] = (int)pkh2((v2 - (float)(_Float16)v2) * ls, (v3 - (float)(_Float16)v3) * ls);
        *(i32x2*)(lo + swz(m * 512 + n * 2, m, 31)) = w;
      }
    }
}

DEV void write_hc(char* hi, f32x16 acc[2][2], int lane, int nbase) {
  const int mr = lane & 31, hh = lane >> 5;
#pragma unroll
  for (int nt = 0; nt < 2; ++nt)
#pragma unroll
    for (int mt = 0; mt < 2; ++mt) {
      int m = mt * 32 + mr;
#pragma unroll
      for (int g = 0; g < 4; ++g) {
        int n = nbase + nt * 32 + 8 * g + 4 * hh;
        i32x2 w;
        w[0] = (int)pkh2(fmaxf(acc[nt][mt][4 * g + 0], 0.f), fmaxf(acc[nt][mt][4 * g + 1], 0.f));
        w[1] = (int)pkh2(fmaxf(acc[nt][mt][4 * g + 2], 0.f), fmaxf(acc[nt][mt][4 * g + 3], 0.f));
        *(i32x2*)(hi + swz(m * 512 + n * 2, m, 31)) = w;
      }
    }
}

// fp32 D[n][m] -> [64][128]f32 RS512 @ACT
DEV void write_f32v(char* dst, const f32x16& a0, const f32x16& a1, int lane, int nbase) {
  const int mr = lane & 31, hh = lane >> 5;
#pragma unroll
  for (int mt = 0; mt < 2; ++mt) {
    const f32x16& a = mt ? a1 : a0;
    int m = mt * 32 + mr;
#pragma unroll
    for (int g = 0; g < 4; ++g) {
      int n = nbase + 8 * g + 4 * hh;
      f32x4 v = { a[4 * g + 0], a[4 * g + 1], a[4 * g + 2], a[4 * g + 3] };
      *(f32x4*)(dst + swz(m * 512 + n * 4, m, 31)) = v;
    }
  }
}

DEV void read_kv(const char* sm, int m, int cs, float* kv) {
#pragma unroll
  for (int blk = 0; blk < 8; ++blk) {
    f32x4 v = *(const f32x4*)(sm + ACT + swz(m * 512 + cs * 128 + blk * 16, m, 31));
    kv[4 * blk] = v[0]; kv[4 * blk + 1] = v[1]; kv[4 * blk + 2] = v[2]; kv[4 * blk + 3] = v[3];
  }
}

// owners: 8 staged values -> hi fp16 @ACT + lo*32 fp16 @SLO (RS256 swz15)
DEV void write_stage8(char* sm, int m, int cs, int gg, const float* sv) {
  i32x4 wh, wl;
#pragma unroll
  for (int j = 0; j < 4; ++j) {
    float v0 = sv[2 * j], v1 = sv[2 * j + 1];
    _Float16 h0 = (_Float16)v0, h1 = (_Float16)v1;
    f16x2 ph = { h0, h1 };
    f16x2 pl = { (_Float16)((v0 - (float)h0) * S5), (_Float16)((v1 - (float)h1) * S5) };
    wh[j] = __builtin_bit_cast(int, ph);
    wl[j] = __builtin_bit_cast(int, pl);
  }
  int off = swz(m * 256 + cs * 64 + gg * 16, m, 15);
  *(i32x4*)(sm + ACT + off) = wh;
  *(i32x4*)(sm + SLO + off) = wl;
}

// ---- one MLP eval: s -> f.  W1 hi+lo8 regs; W2/W3 hi streamed from d_in (cached);
//      W2/W3 lo fp8 LDS tables.  NO d_ws, NO uncached traffic. ----
DEV void f_eval(char* sm, float t,
                const f16x8 (&W1h)[16], const i32x2 (&W1l8)[16], const f16x8 (&Au)[2],
                const float* __restrict__ W2, const float* __restrict__ W3,
                int lane, int wave) {
  const int mr = lane & 31, kh = (lane >> 5) * 8, hh = lane >> 5;
  const int wb64 = wave * 64, wb32 = wave * 32;

  __syncthreads();  // A: stage visible
  f32x16 a1[2][2];
#pragma unroll
  for (int nt = 0; nt < 2; ++nt)
#pragma unroll
    for (int mt = 0; mt < 2; ++mt)
#pragma unroll
      for (int r = 0; r < 16; ++r) a1[nt][mt][r] = 0.f;

#pragma unroll
  for (int ks = 0; ks < 8; ++ks) {
    int ke = ks * 16 + kh;
    f16x8 bh0 = read_f16t(sm + ACT, 256, mr, ke, 15);
    f16x8 bh1 = read_f16t(sm + ACT, 256, 32 + mr, ke, 15);
    f16x8 bl0 = read_f16t(sm + SLO, 256, mr, ke, 15);
    f16x8 bl1 = read_f16t(sm + SLO, 256, 32 + mr, ke, 15);
    f16x8 bh0m = mulh(bh0, IS6), bh1m = mulh(bh1, IS6);
    f16x8 h0 = W1h[ks], h1 = W1h[8 + ks];
    f16x8 w1s0 = mulh(h0, IS5), w1s1 = mulh(h1, IS5);
    f16x8 l0 = dec8(W1l8[ks], IS5), l1 = dec8(W1l8[8 + ks], IS5);   // W1_lo*64
    // term1: s_hi @ W1_hi
    a1[0][0] = MFMA16(h0, bh0, a1[0][0]);
    a1[0][1] = MFMA16(h0, bh1, a1[0][1]);
    a1[1][0] = MFMA16(h1, bh0, a1[1][0]);
    a1[1][1] = MFMA16(h1, bh1, a1[1][1]);
    // term2: (s_lo*32) @ (W1_hi/32)
    a1[0][0] = MFMA16(w1s0, bl0, a1[0][0]);
    a1[0][1] = MFMA16(w1s0, bl1, a1[0][1]);
    a1[1][0] = MFMA16(w1s1, bl0, a1[1][0]);
    a1[1][1] = MFMA16(w1s1, bl1, a1[1][1]);
    // term3: (s_hi/64) @ (W1_lo*64)
    a1[0][0] = MFMA16(l0, bh0m, a1[0][0]);
    a1[0][1] = MFMA16(l0, bh1m, a1[0][1]);
    a1[1][0] = MFMA16(l1, bh0m, a1[1][0]);
    a1[1][1] = MFMA16(l1, bh1m, a1[1][1]);
  }
  // U-slice: U0 + t*U1 at ~fp32
  {
    _Float16 th = (_Float16)t;
    _Float16 tl = (_Float16)(t - (float)th);
    f16x8 ub, ul;
#pragma unroll
    for (int j = 0; j < 8; ++j) { ub[j] = (_Float16)0.f; ul[j] = (_Float16)0.f; }
    if (kh == 0) {
      ub[0] = (_Float16)1.0f; ub[1] = th;
      ub[2] = (_Float16)IS8;  ub[3] = (_Float16)((float)th * IS8);
      ul[1] = tl;             ul[3] = (_Float16)((float)tl * IS8);
    }
#pragma unroll
    for (int nt = 0; nt < 2; ++nt) {
      a1[nt][0] = MFMA16(Au[nt], ub, a1[nt][0]);
      a1[nt][1] = MFMA16(Au[nt], ub, a1[nt][1]);
      a1[nt][0] = MFMA16(Au[nt], ul, a1[nt][0]);
      a1[nt][1] = MFMA16(Au[nt], ul, a1[nt][1]);
    }
  }
  __syncthreads();  // G1: s reads done
  write_h8(sm + ACT, sm + ALO, a1, lane, wb64);
  __syncthreads();  // C: h1 ready

  // ---- layer 2: W2 hi streamed from global f32 (depth-2), W2 lo fp8 LDS ----
  const float* B2p = (const float*)(sm + B2O);
  f32x16 a2[2][2];
#pragma unroll
  for (int nt = 0; nt < 2; ++nt)
#pragma unroll
    for (int g = 0; g < 4; ++g) {
      int n = wb64 + nt * 32 + 8 * g + 4 * hh;
      f32x4 bv = *(const f32x4*)(B2p + n);
#pragma unroll
      for (int r = 0; r < 4; ++r) { a2[nt][0][4 * g + r] = bv[r]; a2[nt][1][4 * g + r] = bv[r]; }
    }
  const float* w2r0 = W2 + (size_t)(wb64 + mr) * 256 + kh;
  const float* w2r1 = W2 + (size_t)(wb64 + 32 + mr) * 256 + kh;
  f32x4 w2b[2][2][2];   // [slot][nt][half]
#pragma unroll
  for (int s = 0; s < 2; ++s) {
    w2b[s][0][0] = *(const f32x4*)(w2r0 + s * 16);
    w2b[s][0][1] = *(const f32x4*)(w2r0 + s * 16 + 4);
    w2b[s][1][0] = *(const f32x4*)(w2r1 + s * 16);
    w2b[s][1][1] = *(const f32x4*)(w2r1 + s * 16 + 4);
  }
#pragma unroll
  for (int ks = 0; ks < 16; ++ks) {
    f16x8 W2h0 = cvt8v(w2b[ks & 1][0][0], w2b[ks & 1][0][1]);
    f16x8 W2h1 = cvt8v(w2b[ks & 1][1][0], w2b[ks & 1][1][1]);
    if (ks + 2 < 16) {
      w2b[ks & 1][0][0] = *(const f32x4*)(w2r0 + (ks + 2) * 16);
      w2b[ks & 1][0][1] = *(const f32x4*)(w2r0 + (ks + 2) * 16 + 4);
      w2b[ks & 1][1][0] = *(const f32x4*)(w2r1 + (ks + 2) * 16);
      w2b[ks & 1][1][1] = *(const f32x4*)(w2r1 + (ks + 2) * 16 + 4);
    }
    int ke = ks * 16 + kh;
    f16x8 bh0 = read_f16t(sm + ACT, 512, mr, ke, 31);
    f16x8 bh1 = read_f16t(sm + ACT, 512, 32 + mr, ke, 31);
    f16x8 bl0 = dec8(read8b(sm + ALO, mr, ke), IS6);      // h1_lo*32
    f16x8 bl1 = dec8(read8b(sm + ALO, 32 + mr, ke), IS6);
    f16x8 w2s0 = mulh(W2h0, IS5), w2s1 = mulh(W2h1, IS5);
    f16x8 bh0m = mulh(bh0, IS6), bh1m = mulh(bh1, IS6);
    i32x2 t0 = *(const i32x2*)(sm + W2L + ((size_t)((wave * 2 + 0) * 16 + ks) * 64 + lane) * 8);
    i32x2 t1 = *(const i32x2*)(sm + W2L + ((size_t)((wave * 2 + 1) * 16 + ks) * 64 + lane) * 8);
    f16x8 wa0 = dec8(t0, IS5), wa1 = dec8(t1, IS5);       // W2_lo*64
    a2[0][0] = MFMA16(W2h0, bh0, a2[0][0]);
    a2[0][1] = MFMA16(W2h0, bh1, a2[0][1]);
    a2[1][0] = MFMA16(W2h1, bh0, a2[1][0]);
    a2[1][1] = MFMA16(W2h1, bh1, a2[1][1]);
    a2[0][0] = MFMA16(w2s0, bl0, a2[0][0]);
    a2[0][1] = MFMA16(w2s0, bl1, a2[0][1]);
    a2[1][0] = MFMA16(w2s1, bl0, a2[1][0]);
    a2[1][1] = MFMA16(w2s1, bl1, a2[1][1]);
    a2[0][0] = MFMA16(wa0, bh0m, a2[0][0]);
    a2[0][1] = MFMA16(wa0, bh1m, a2[0][1]);
    a2[1][0] = MFMA16(wa1, bh0m, a2[1][0]);
    a2[1][1] = MFMA16(wa1, bh1m, a2[1][1]);
  }
  __syncthreads();  // G2: h1 reads done
  write_h8(sm + ACT, sm + ALO, a2, lane, wb64);
  __syncthreads();  // E: h2 ready

  // ---- layer 3: W3 hi streamed from global f32 (depth-2), W3 lo fp8 LDS ----
  const float* B3p = (const float*)(sm + B3O);
  f32x16 a30, a31;
#pragma unroll
  for (int g = 0; g < 4; ++g) {
    int n = wb32 + 8 * g + 4 * hh;
    f32x4 bv = *(const f32x4*)(B3p + n);
#pragma unroll
    for (int r = 0; r < 4; ++r) { a30[4 * g + r] = bv[r]; a31[4 * g + r] = bv[r]; }
  }
  const float* w3r = W3 + (size_t)(wb32 + mr) * 256 + kh;
  f32x4 w3b[2][2];   // [slot][half]
#pragma unroll
  for (int s = 0; s < 2; ++s) {
    w3b[s][0] = *(const f32x4*)(w3r + s * 16);
    w3b[s][1] = *(const f32x4*)(w3r + s * 16 + 4);
  }
#pragma unroll
  for (int ks = 0; ks < 16; ++ks) {
    f16x8 W3h = cvt8v(w3b[ks & 1][0], w3b[ks & 1][1]);
    if (ks + 2 < 16) {
      w3b[ks & 1][0] = *(const f32x4*)(w3r + (ks + 2) * 16);
      w3b[ks & 1][1] = *(const f32x4*)(w3r + (ks + 2) * 16 + 4);
    }
    int ke = ks * 16 + kh;
    f16x8 bh0 = read_f16t(sm + ACT, 512, mr, ke, 31);
    f16x8 bh1 = read_f16t(sm + ACT, 512, 32 + mr, ke, 31);
    f16x8 bl0 = dec8(read8b(sm + ALO, mr, ke), IS6);
    f16x8 bl1 = dec8(read8b(sm + ALO, 32 + mr, ke), IS6);
    f16x8 w3s = mulh(W3h, IS5);
    f16x8 bh0m = mulh(bh0, IS6), bh1m = mulh(bh1, IS6);
    i32x2 t0 = *(const i32x2*)(sm + W3L + ((size_t)(wave * 16 + ks) * 64 + lane) * 8);
    f16x8 wa = dec8(t0, IS5);
    a30 = MFMA16(W3h, bh0, a30);
    a31 = MFMA16(W3h, bh1, a31);
    a30 = MFMA16(w3s, bl0, a30);
    a31 = MFMA16(w3s, bl1, a31);
    a30 = MFMA16(wa, bh0m, a30);
    a31 = MFMA16(wa, bh1m, a31);
  }
  __syncthreads();  // G3: h2 reads done
  write_f32v(sm + ACT, a30, a31, lane, wb32);
  __syncthreads();  // F: f ready
}

__global__ __launch_bounds__(256, 1) void node_kernel(
    const float* __restrict__ traj,
    const float* __restrict__ We1, const float* __restrict__ be1,
    const float* __restrict__ We2, const float* __restrict__ be2,
    const float* __restrict__ wte, const float* __restrict__ bte,
    const float* __restrict__ W1,  const float* __restrict__ b1,
    const float* __restrict__ W2,  const float* __restrict__ b2,
    const float* __restrict__ W3,  const float* __restrict__ b3,
    const float* __restrict__ Wc1, const float* __restrict__ bc1,
    const float* __restrict__ Wc2, const float* __restrict__ bc2,
    float* __restrict__ out) {
  __shared__ __align__(16) char sm[SMEM_BYTES];
  const int tid  = threadIdx.x;
  const int lane = tid & 63, wave = tid >> 6;
  const int mr = lane & 31, kh = (lane >> 5) * 8, hh = lane >> 5;
  const int wb64 = wave * 64, wb32 = wave * 32;
  const int brow = blockIdx.x * 64;

  // ---- init: U0/U1 fold, bias tables ----
  {
    int n = tid;
    float u0 = b1[n], u1 = 0.f;
    const float* wr = W1 + n * 128;
    for (int k = 0; k < 128; ++k) { float w = wr[k]; u1 += wte[k] * w; u0 += bte[k] * w; }
    float* U = (float*)(sm + U01O);
    U[2 * n] = u0; U[2 * n + 1] = u1;
    ((float*)(sm + B2O))[n] = b2[n];
    if (n < 128) ((float*)(sm + B3O))[n] = b3[n];
  }

  // ---- resident: W1 hi fp16 + lo fp8 in registers ----
  f16x8 W1h[16], Au[2];
  i32x2 W1l8[16];
#pragma unroll
  for (int nt = 0; nt < 2; ++nt)
#pragma unroll
    for (int ks = 0; ks < 8; ++ks)
      cvt_h8(W1 + (size_t)(wb64 + nt * 32 + mr) * 128 + ks * 16 + kh,
             W1h[nt * 8 + ks], W1l8[nt * 8 + ks]);

  __syncthreads();  // U01 ready

  // Au: rows n, slots [U0h, U1h, U0l*256, U1l*256]
#pragma unroll
  for (int nt = 0; nt < 2; ++nt) {
    f16x8 a;
#pragma unroll
    for (int j = 0; j < 8; ++j) a[j] = (_Float16)0.f;
    if (kh == 0) {
      const float* U = (const float*)(sm + U01O);
      int n = wb64 + nt * 32 + mr;
      float u0 = U[2 * n], u1 = U[2 * n + 1];
      _Float16 u0h = (_Float16)u0, u1h = (_Float16)u1;
      a[0] = u0h; a[1] = u1h;
      a[2] = (_Float16)((u0 - (float)u0h) * S8);
      a[3] = (_Float16)((u1 - (float)u1h) * S8);
    }
    Au[nt] = a;
  }

  const int m_own = tid >> 2, cs = tid & 3;

  // ---- encoder: x hi@ACT RS512, x lo*64 @W2L scratch RS512 ----
  f32x16 ae[2][2];
#pragma unroll
  for (int nt = 0; nt < 2; ++nt)
#pragma unroll
    for (int mt = 0; mt < 2; ++mt)
#pragma unroll
      for (int r = 0; r < 16; ++r) ae[nt][mt][r] = 0.f;

  for (int c = 0; c < 3; ++c) {
#pragma unroll
    for (int g = 0; g < 8; ++g) {
      const float* xp = traj + (size_t)(brow + m_own) * 7168 + c * 256 + cs * 64 + g * 8;
      f32x4 a = *(const f32x4*)xp;
      f32x4 b = *(const f32x4*)(xp + 4);
      i32x4 wh, wl;
#pragma unroll
      for (int j = 0; j < 2; ++j) {
        float v0 = a[2 * j], v1 = a[2 * j + 1];
        _Float16 h0 = (_Float16)v0, h1 = (_Float16)v1;
        f16x2 ph = { h0, h1 };
        f16x2 pl = { (_Float16)((v0 - (float)h0) * S6), (_Float16)((v1 - (float)h1) * S6) };
        wh[j] = __builtin_bit_cast(int, ph); wl[j] = __builtin_bit_cast(int, pl);
        float w0 = b[2 * j], w1 = b[2 * j + 1];
        _Float16 g0 = (_Float16)w0, g1 = (_Float16)w1;
        f16x2 qh = { g0, g1 };
        f16x2 ql = { (_Float16)((w0 - (float)g0) * S6), (_Float16)((w1 - (float)g1) * S6) };
        wh[2 + j] = __builtin_bit_cast(int, qh); wl[2 + j] = __builtin_bit_cast(int, ql);
      }
      int off = swz(m_own * 512 + cs * 128 + g * 16, m_own, 31);
      *(i32x4*)(sm + ACT + off) = wh;
      *(i32x4*)(sm + W2L + off) = wl;
    }
    __syncthreads();
#pragma unroll
    for (int ks = 0; ks < 16; ++ks) {
      int ke = ks * 16 + kh;
      f16x8 bh0 = read_f16t(sm + ACT, 512, mr, ke, 31);
      f16x8 bh1 = read_f16t(sm + ACT, 512, 32 + mr, ke, 31);
      f16x8 bl0 = read_f16t(sm + W2L, 512, mr, ke, 31);
      f16x8 bl1 = read_f16t(sm + W2L, 512, 32 + mr, ke, 31);
      f16x8 bh0m = mulh(bh0, IS6), bh1m = mulh(bh1, IS6);
#pragma unroll
      for (int nt = 0; nt < 2; ++nt) {
        f16x8 wh, wl;
        cvt_hl_s(We1 + (size_t)(wb64 + nt * 32 + mr) * 768 + c * 256 + ks * 16 + kh, wh, wl, S6);
        f16x8 whs = mulh(wh, IS6);
        ae[nt][0] = MFMA16(wh, bh0, ae[nt][0]);
        ae[nt][1] = MFMA16(wh, bh1, ae[nt][1]);
        ae[nt][0] = MFMA16(whs, bl0, ae[nt][0]);
        ae[nt][1] = MFMA16(whs, bl1, ae[nt][1]);
        ae[nt][0] = MFMA16(wl, bh0m, ae[nt][0]);
        ae[nt][1] = MFMA16(wl, bh1m, ae[nt][1]);
      }
    }
    __syncthreads();
  }
#pragma unroll
  for (int nt = 0; nt < 2; ++nt)
#pragma unroll
    for (int r = 0; r < 16; ++r) {
      int n = wb64 + nt * 32 + (r & 3) + 8 * (r >> 2) + 4 * hh;
      float bv = be1[n];
      ae[nt][0][r] += bv; ae[nt][1][r] += bv;
    }
  write_h16(sm + ACT, sm + W2L, ae, lane, wb64, S6);   // h_enc hi@ACT, lo*64@W2L scratch
  __syncthreads();

  {
    f32x16 az0, az1;
#pragma unroll
    for (int r = 0; r < 16; ++r) { az0[r] = 0.f; az1[r] = 0.f; }
#pragma unroll
    for (int ks = 0; ks < 16; ++ks) {
      int ke = ks * 16 + kh;
      f16x8 bh0 = read_f16t(sm + ACT, 512, mr, ke, 31);
      f16x8 bh1 = read_f16t(sm + ACT, 512, 32 + mr, ke, 31);
      f16x8 bl0 = read_f16t(sm + W2L, 512, mr, ke, 31);
      f16x8 bl1 = read_f16t(sm + W2L, 512, 32 + mr, ke, 31);
      f16x8 bh0m = mulh(bh0, IS6), bh1m = mulh(bh1, IS6);
      f16x8 wh, wl;
      cvt_hl_s(We2 + (size_t)(wb32 + mr) * 256 + ks * 16 + kh, wh, wl, S6);
      f16x8 whs = mulh(wh, IS6);
      az0 = MFMA16(wh, bh0, az0);
      az1 = MFMA16(wh, bh1, az1);
      az0 = MFMA16(whs, bl0, az0);
      az1 = MFMA16(whs, bl1, az1);
      az0 = MFMA16(wl, bh0m, az0);
      az1 = MFMA16(wl, bh1m, az1);
    }
#pragma unroll
    for (int r = 0; r < 16; ++r) {
      int n = wb32 + (r & 3) + 8 * (r >> 2) + 4 * hh;
      float bv = be2[n];
      az0[r] += bv; az1[r] += bv;
    }
    __syncthreads();                    // h_enc reads done
    write_f32v(sm + ACT, az0, az1, lane, wb32);  // z0 in f layout
    __syncthreads();
  }

  // ---- owners pick up z0; write frame 0 ----
  float z[32], Acc[32];
  unsigned kdp[16];
  read_kv(sm, m_own, cs, z);
  float* outz = out + 16384;
  {
    float* p = outz + (size_t)(brow + m_own) * 128 + cs * 32;
#pragma unroll
    for (int g = 0; g < 8; ++g) {
      f32x4 v = { z[4 * g], z[4 * g + 1], z[4 * g + 2], z[4 * g + 3] };
      *(f32x4*)(p + 4 * g) = v;
    }
  }

  // ---- fill W2_lo / W3_lo fp8 tables (W2L region was encoder scratch) ----
#pragma unroll
  for (int nt = 0; nt < 2; ++nt)
    for (int ks = 0; ks < 16; ++ks) {
      f16x8 hi; i32x2 lo8;
      cvt_h8(W2 + (size_t)(wb64 + nt * 32 + mr) * 256 + ks * 16 + kh, hi, lo8);
      *(i32x2*)(sm + W2L + ((size_t)((wave * 2 + nt) * 16 + ks) * 64 + lane) * 8) = lo8;
    }
  for (int ks = 0; ks < 16; ++ks) {
    f16x8 hi; i32x2 lo8;
    cvt_h8(W3 + (size_t)(wb32 + mr) * 256 + ks * 16 + kh, hi, lo8);
    *(i32x2*)(sm + W3L + ((size_t)(wave * 16 + ks) * 64 + lane) * 8) = lo8;
  }

  // ---- RK4 (3/8 rule), 54 steps ----
  for (int st = 0; st < 54; ++st) {
    float t0 = st * 0.5f;
    __syncthreads();  // H: f/z0 reads done; tables visible (st==0)
#pragma unroll
    for (int gg = 0; gg < 4; ++gg) write_stage8(sm, m_own, cs, gg, z + 8 * gg);  // s1 = z
    f_eval(sm, t0, W1h, W1l8, Au, W2, W3, lane, wave);          // k1
    {
      float kv[32];
      read_kv(sm, m_own, cs, kv);
      __syncthreads();
#pragma unroll
      for (int i = 0; i < 16; ++i) kdp[i] = pkh2(kv[2 * i], kv[2 * i + 1]);
#pragma unroll
      for (int gg = 0; gg < 4; ++gg) {
        float sv[8];
#pragma unroll
        for (int j = 0; j < 8; ++j) {
          int e = 8 * gg + j;
          Acc[e] = z[e] + DT8 * kv[e];
          sv[j] = z[e] + DT3 * kv[e];
        }
        write_stage8(sm, m_own, cs, gg, sv);
      }
    }
    f_eval(sm, t0 + DT3, W1h, W1l8, Au, W2, W3, lane, wave);    // k2
    {
      float kv[32];
      read_kv(sm, m_own, cs, kv);
      __syncthreads();
#pragma unroll
      for (int gg = 0; gg < 4; ++gg) {
        float sv[8];
#pragma unroll
        for (int q = 0; q < 4; ++q) {
          int i = 4 * gg + q;
          float k1a = upkh(kdp[i], 0), k1b = upkh(kdp[i], 1);
          float k2a = kv[2 * i], k2b = kv[2 * i + 1];
          Acc[2 * i]     += 3.0f * DT8 * k2a;
          Acc[2 * i + 1] += 3.0f * DT8 * k2b;
          sv[2 * q]     = z[2 * i]     + DT * k2a - DT3 * k1a;
          sv[2 * q + 1] = z[2 * i + 1] + DT * k2b - DT3 * k1b;
          kdp[i] = pkh2(k1a - k2a, k1b - k2b);   // d12
        }
        write_stage8(sm, m_own, cs, gg, sv);
      }
    }
    f_eval(sm, t0 + 2.0f * DT3, W1h, W1l8, Au, W2, W3, lane, wave);  // k3
    {
      float kv[32];
      read_kv(sm, m_own, cs, kv);
      __syncthreads();
#pragma unroll
      for (int gg = 0; gg < 4; ++gg) {
        float sv[8];
#pragma unroll
        for (int q = 0; q < 4; ++q) {
          int i = 4 * gg + q;
          float da = upkh(kdp[i], 0), db = upkh(kdp[i], 1);
          Acc[2 * i]     += 3.0f * DT8 * kv[2 * i];
          Acc[2 * i + 1] += 3.0f * DT8 * kv[2 * i + 1];
          sv[2 * q]     = z[2 * i]     + DT * (da + kv[2 * i]);
          sv[2 * q + 1] = z[2 * i + 1] + DT * (db + kv[2 * i + 1]);
        }
        write_stage8(sm, m_own, cs, gg, sv);
      }
    }
    f_eval(sm, t0 + DT, W1h, W1l8, Au, W2, W3, lane, wave);     // k4
    {
      float kv[32];
      read_kv(sm, m_own, cs, kv);
#pragma unroll
      for (int e = 0; e < 32; ++e) z[e] = Acc[e] + DT8 * kv[e];
    }
    if (st & 1) {
      int frame = (st >> 1) + 1;
      float* p = outz + (size_t)frame * 2097152 + (size_t)(brow + m_own) * 128 + cs * 32;
#pragma unroll
      for (int g = 0; g < 8; ++g) {
        f32x4 v = { z[4 * g], z[4 * g + 1], z[4 * g + 2], z[4 * g + 3] };
        *(f32x4*)(p + 4 * g) = v;
      }
    }
  }

  // ---- classifier ----
  __syncthreads();  // f reads done
#pragma unroll
  for (int gg = 0; gg < 4; ++gg) write_stage8(sm, m_own, cs, gg, z + 8 * gg);
  __syncthreads();
  f32x16 ac[2][2];
#pragma unroll
  for (int nt = 0; nt < 2; ++nt)
#pragma unroll
    for (int r = 0; r < 16; ++r) {
      int n = wb64 + nt * 32 + (r & 3) + 8 * (r >> 2) + 4 * hh;
      float bv = bc1[n];
      ac[nt][0][r] = bv; ac[nt][1][r] = bv;
    }
#pragma unroll
  for (int ks = 0; ks < 8; ++ks) {
    int ke = ks * 16 + kh;
    f16x8 bh0 = read_f16t(sm + ACT, 256, mr, ke, 15);
    f16x8 bh1 = read_f16t(sm + ACT, 256, 32 + mr, ke, 15);
    f16x8 bl0 = read_f16t(sm + SLO, 256, mr, ke, 15);
    f16x8 bl1 = read_f16t(sm + SLO, 256, 32 + mr, ke, 15);
#pragma unroll
    for (int nt = 0; nt < 2; ++nt) {
      f16x8 wh, wl;
      cvt_hl_s(Wc1 + (size_t)(wb64 + nt * 32 + mr) * 128 + ks * 16 + kh, wh, wl, 1.0f);
      f16x8 whs = mulh(wh, IS5);
      ac[nt][0] = MFMA16(wh, bh0, ac[nt][0]);
      ac[nt][1] = MFMA16(wh, bh1, ac[nt][1]);
      ac[nt][0] = MFMA16(whs, bl0, ac[nt][0]);
      ac[nt][1] = MFMA16(whs, bl1, ac[nt][1]);
      ac[nt][0] = MFMA16(wl, bh0, ac[nt][0]);
      ac[nt][1] = MFMA16(wl, bh1, ac[nt][1]);
    }
  }
  __syncthreads();  // s reads done
  write_hc(sm + ACT, ac, lane, wb64);
  __syncthreads();
  if (tid < 64) {
    float acc = bc2[0];
#pragma unroll 8
    for (int c0 = 0; c0 < 256; c0 += 8) {
      f16x8 hv = read_f16t(sm + ACT, 512, tid, c0, 31);
#pragma unroll
      for (int j = 0; j < 8; ++j) acc += (float)hv[j] * Wc2[c0 + j];
    }
    out[brow + tid] = __builtin_amdgcn_rcpf(1.0f + __builtin_amdgcn_exp2f(-acc * 1.442695041f));
  }
}

extern "C" void kernel_launch(void* const* d_in, const int* in_sizes, int n_in,
                              void* d_out, int out_size, void* d_ws, size_t ws_size,
                              hipStream_t stream) {
  (void)in_sizes; (void)n_in; (void)out_size; (void)d_ws; (void)ws_size;
  const float* traj = (const float*)d_in[0];
  const float* We1  = (const float*)d_in[1];
  const float* be1  = (const float*)d_in[2];
  const float* We2  = (const float*)d_in[3];
  const float* be2  = (const float*)d_in[4];
  const float* wte  = (const float*)d_in[5];
  const float* bte  = (const float*)d_in[6];
  const float* W1   = (const float*)d_in[7];
  const float* b1   = (const float*)d_in[8];
  const float* W2   = (const float*)d_in[9];
  const float* b2   = (const float*)d_in[10];
  const float* W3   = (const float*)d_in[11];
  const float* b3   = (const float*)d_in[12];
  const float* Wc1  = (const float*)d_in[13];
  const float* bc1  = (const float*)d_in[14];
  const float* Wc2  = (const float*)d_in[15];
  const float* bc2  = (const float*)d_in[16];
  hipLaunchKernelGGL(node_kernel, dim3(256), dim3(256), 0, stream,
                     traj, We1, be1, We2, be2, wte, bte, W1, b1, W2, b2, W3, b3,
                     Wc1, bc1, Wc2, bc2, (float*)d_out);
}